// Round 2
// baseline (162.982 us; speedup 1.0000x reference)
//
#include <hip/hip_runtime.h>
#include <hip/hip_bf16.h>

#define HDIM 2048
#define HH (HDIM * HDIM)          // 4,194,304 pixels per plane
#define NBINS 256
#define KCNT 1048576.0f           // K_SRC == K_TAR == HH/4 (exactly 2^20)
#define TOTAL_ELEMS 12582912.0    // 3 * H * H

// Per-block partial row: 1536 int counts (rows 0-2 dst, 3-5 ref) + 768 float
// value-sums (dst channels only) = 2304 dwords = 9216 bytes.
#define ROW_DWORDS 2304
#define ROW_BYTES  9216

__device__ __forceinline__ float de_norm255(float x) {
    float v = (x + 1.0f) * 0.5f;               // /2.0 == *0.5 exactly in f32
    v = fminf(fmaxf(v, 0.0f), 1.0f) * 255.0f;  // in [0, 255]
    return v;
}

// Kernel 1: per-block private histograms + per-bin value sums, no global atomics.
// Clipped values (v==0 -> bin 0, v==255 -> bin 255) counted in registers:
// they contribute 0 (resp. 255*n, derived later) to the value sums, so the
// hot bins never touch LDS atomics in the inner loop.
__global__ void hist_kernel(const float* __restrict__ inp,
                            const float* __restrict__ tar,
                            const float* __restrict__ msrc,
                            const float* __restrict__ mtar,
                            int* __restrict__ parts) {
    __shared__ int   lcnt[6 * NBINS];
    __shared__ float lsum[3 * NBINS];
    for (int i = threadIdx.x; i < 6 * NBINS; i += blockDim.x) lcnt[i] = 0;
    for (int i = threadIdx.x; i < 3 * NBINS; i += blockDim.x) lsum[i] = 0.0f;
    __syncthreads();

    int nz[6] = {0, 0, 0, 0, 0, 0};   // bin-0 counts   (rows 0-2 dst, 3-5 ref)
    int nf[6] = {0, 0, 0, 0, 0, 0};   // bin-255 counts

    const int stride = gridDim.x * blockDim.x;
    const int n4 = HH / 4;
    for (int p4 = blockIdx.x * blockDim.x + threadIdx.x; p4 < n4; p4 += stride) {
        float4 ms4 = ((const float4*)msrc)[p4];
        float4 mt4 = ((const float4*)mtar)[p4];
        float m[4] = {ms4.x, ms4.y, ms4.z, ms4.w};
        float t[4] = {mt4.x, mt4.y, mt4.z, mt4.w};
        #pragma unroll
        for (int c = 0; c < 3; ++c) {
            float4 v4 = ((const float4*)(inp + (size_t)c * HH))[p4];
            float4 w4 = ((const float4*)(tar + (size_t)c * HH))[p4];
            float vv[4] = {v4.x, v4.y, v4.z, v4.w};
            float ww[4] = {w4.x, w4.y, w4.z, w4.w};
            #pragma unroll
            for (int k = 0; k < 4; ++k) {
                if (m[k] != 0.0f) {
                    float v = de_norm255(vv[k]);
                    if (v == 0.0f)         nz[c]++;
                    else if (v == 255.0f)  nf[c]++;
                    else {
                        int b = (int)v;    // 1..254 range guaranteed non-hot path? (b in [0,254])
                        atomicAdd(&lcnt[c * NBINS + b], 1);
                        atomicAdd(&lsum[c * NBINS + b], v);
                    }
                }
                if (t[k] != 0.0f) {
                    float v = de_norm255(ww[k]);
                    if (v == 0.0f)         nz[3 + c]++;
                    else if (v == 255.0f)  nf[3 + c]++;
                    else {
                        int b = (int)v;
                        atomicAdd(&lcnt[(3 + c) * NBINS + b], 1);
                    }
                }
            }
        }
    }

    // wave-reduce the 12 register counters, one LDS atomic per wave each
    #pragma unroll
    for (int j = 0; j < 6; ++j) {
        int a = nz[j], f = nf[j];
        #pragma unroll
        for (int off = 32; off > 0; off >>= 1) {
            a += __shfl_down(a, off, 64);
            f += __shfl_down(f, off, 64);
        }
        if ((threadIdx.x & 63) == 0) {
            if (a) atomicAdd(&lcnt[j * NBINS + 0], a);
            if (f) atomicAdd(&lcnt[j * NBINS + NBINS - 1], f);
        }
    }
    __syncthreads();

    // coalesced flush of this block's partial row (full overwrite -> no memset)
    int* row = parts + (size_t)blockIdx.x * ROW_DWORDS;
    for (int i = threadIdx.x; i < ROW_DWORDS; i += blockDim.x)
        row[i] = (i < 6 * NBINS) ? lcnt[i] : __float_as_int(lsum[i - 6 * NBINS]);
}

// Kernel 2: deterministic column reduction of the partials.
__global__ void reduce_kernel(const int* __restrict__ parts, int nblk,
                              int* __restrict__ counts,
                              double* __restrict__ sums) {
    int j = blockIdx.x * blockDim.x + threadIdx.x;
    if (j >= ROW_DWORDS) return;
    if (j < 6 * NBINS) {
        int acc = 0;
        for (int w = 0; w < nblk; ++w) acc += parts[(size_t)w * ROW_DWORDS + j];
        counts[j] = acc;
    } else {
        double acc = 0.0;
        for (int w = 0; w < nblk; ++w)
            acc += (double)__int_as_float(parts[(size_t)w * ROW_DWORDS + j]);
        sums[j - 6 * NBINS] = acc;
    }
}

// Kernel 3: cdf (bit-exact serial f32 cumsum) + searchsorted table + analytic loss.
// Within bin b, v in [b, b+1) and t integer => |v-t| sign fixed per bin:
//   t <= b : sum = s_b - n_b*t ;  t >= b+1 : sum = n_b*t - s_b.
__global__ void final_kernel(const int* __restrict__ counts,
                             const double* __restrict__ sums,
                             float* __restrict__ out) {
    __shared__ float cdf[6][NBINS];
    __shared__ int   lcnt[6 * NBINS];
    __shared__ double red[12];
    const int tid = threadIdx.x;           // 768 threads
    lcnt[tid]       = counts[tid];
    lcnt[tid + 768] = counts[tid + 768];
    __syncthreads();

    if (tid < 6) {
        // pdf = count / 2^20 is exact; serial f32 cumsum matches the reference
        float run = 0.0f;
        for (int i = 0; i < NBINS; ++i) {
            run += (float)lcnt[tid * NBINS + i] * (1.0f / KCNT);
            cdf[tid][i] = run;
        }
    }
    __syncthreads();

    const int c = tid >> 8, b = tid & (NBINS - 1);
    const float d = cdf[c][b];
    const float* r = cdf[3 + c];
    // searchsorted(r, d, side='left'): first j with r[j] >= d
    int lo = 0, hi = NBINS;
    while (lo < hi) {
        int mid = (lo + hi) >> 1;
        if (r[mid] < d) lo = mid + 1; else hi = mid;
    }
    int j = lo;
    if (j < 1) j = 1;
    if (j > NBINS - 1) j = NBINS - 1;
    bool valid = (r[j - 1] <= d) && (d <= r[j]);
    int t = valid ? j : b;
    if (b == NBINS - 1) t = NBINS - 1;

    const int n = lcnt[c * NBINS + b];
    const double s = (b == NBINS - 1) ? 255.0 * (double)n : sums[c * NBINS + b];
    double contrib = (t <= b) ? (s - (double)n * (double)t)
                              : ((double)n * (double)t - s);

    #pragma unroll
    for (int off = 32; off > 0; off >>= 1)
        contrib += __shfl_down(contrib, off, 64);
    const int wave = tid >> 6, lane = tid & 63;
    if (lane == 0) red[wave] = contrib;
    __syncthreads();
    if (tid == 0) {
        double tot = 0.0;
        for (int w = 0; w < 12; ++w) tot += red[w];
        out[0] = (float)(tot / TOTAL_ELEMS);
    }
}

extern "C" void kernel_launch(void* const* d_in, const int* in_sizes, int n_in,
                              void* d_out, int out_size, void* d_ws, size_t ws_size,
                              hipStream_t stream) {
    const float* inp  = (const float*)d_in[0];   // (1,3,H,H)
    const float* tar  = (const float*)d_in[1];   // (1,3,H,H)
    const float* msrc = (const float*)d_in[2];   // (1,1,H,H)
    const float* mtar = (const float*)d_in[3];   // (1,1,H,H)
    float* out = (float*)d_out;

    int nblk = 512;
    // tail: counts (6144 B) + sums (6144 B)
    size_t tail = 6 * NBINS * sizeof(int) + 3 * NBINS * sizeof(double);
    if (ws_size < (size_t)nblk * ROW_BYTES + tail) {
        size_t avail = ws_size > tail ? (ws_size - tail) / ROW_BYTES : 1;
        nblk = avail < 1 ? 1 : (int)avail;
    }

    char* ws = (char*)d_ws;
    int*    parts  = (int*)ws;
    int*    counts = (int*)(ws + (size_t)nblk * ROW_BYTES);
    double* sums   = (double*)(ws + (size_t)nblk * ROW_BYTES + 6 * NBINS * sizeof(int));

    hist_kernel<<<nblk, 256, 0, stream>>>(inp, tar, msrc, mtar, parts);
    reduce_kernel<<<(ROW_DWORDS + 255) / 256, 256, 0, stream>>>(parts, nblk, counts, sums);
    final_kernel<<<1, 3 * NBINS, 0, stream>>>(counts, sums, out);
}

// Round 3
// 52.420 us; speedup vs baseline: 3.1091x; 3.1091x over previous
//
#include <hip/hip_runtime.h>
#include <hip/hip_bf16.h>

#define HDIM 2048
#define HH (HDIM * HDIM)          // 4,194,304 pixels per plane
#define NBINS 256
#define KCNT 1048576.0f           // K_SRC == K_TAR == HH/4 (exactly 2^20)
#define TOTAL_ELEMS 12582912.0    // 3 * H * H

// Per-block partial row: 1536 int counts (rows 0-2 dst, 3-5 ref) + 768 float
// value-sums (dst channels only) = 2304 dwords = 9216 bytes.
#define ROW_DWORDS 2304
#define ROW_BYTES  9216
#define TAIL_BYTES (6 * NBINS * sizeof(int) + 3 * NBINS * sizeof(double))  // 12288
#define ROWS_PER_CHUNK 32

__device__ __forceinline__ float de_norm255(float x) {
    float v = (x + 1.0f) * 0.5f;               // /2.0 == *0.5 exactly in f32
    v = fminf(fmaxf(v, 0.0f), 1.0f) * 255.0f;  // in [0, 255]
    return v;
}

// Kernel 1: per-block private histograms + per-bin value sums, no global atomics.
// Clipped values (v==0 -> bin 0, v==255 -> bin 255) counted in registers:
// zero / 255*n contributions to value sums are derived analytically later,
// so the hot bins never touch LDS atomics in the inner loop.
__global__ void hist_kernel(const float* __restrict__ inp,
                            const float* __restrict__ tar,
                            const float* __restrict__ msrc,
                            const float* __restrict__ mtar,
                            int* __restrict__ parts) {
    __shared__ int   lcnt[6 * NBINS];
    __shared__ float lsum[3 * NBINS];
    for (int i = threadIdx.x; i < 6 * NBINS; i += blockDim.x) lcnt[i] = 0;
    for (int i = threadIdx.x; i < 3 * NBINS; i += blockDim.x) lsum[i] = 0.0f;
    __syncthreads();

    int nz[6] = {0, 0, 0, 0, 0, 0};   // bin-0 counts   (rows 0-2 dst, 3-5 ref)
    int nf[6] = {0, 0, 0, 0, 0, 0};   // bin-255 counts

    const int stride = gridDim.x * blockDim.x;
    const int n4 = HH / 4;
    for (int p4 = blockIdx.x * blockDim.x + threadIdx.x; p4 < n4; p4 += stride) {
        float4 ms4 = ((const float4*)msrc)[p4];
        float4 mt4 = ((const float4*)mtar)[p4];
        float m[4] = {ms4.x, ms4.y, ms4.z, ms4.w};
        float t[4] = {mt4.x, mt4.y, mt4.z, mt4.w};
        #pragma unroll
        for (int c = 0; c < 3; ++c) {
            float4 v4 = ((const float4*)(inp + (size_t)c * HH))[p4];
            float4 w4 = ((const float4*)(tar + (size_t)c * HH))[p4];
            float vv[4] = {v4.x, v4.y, v4.z, v4.w};
            float ww[4] = {w4.x, w4.y, w4.z, w4.w};
            #pragma unroll
            for (int k = 0; k < 4; ++k) {
                if (m[k] != 0.0f) {
                    float v = de_norm255(vv[k]);
                    if (v == 0.0f)         nz[c]++;
                    else if (v == 255.0f)  nf[c]++;
                    else {
                        int b = (int)v;    // b in [0, 254]
                        atomicAdd(&lcnt[c * NBINS + b], 1);
                        atomicAdd(&lsum[c * NBINS + b], v);
                    }
                }
                if (t[k] != 0.0f) {
                    float v = de_norm255(ww[k]);
                    if (v == 0.0f)         nz[3 + c]++;
                    else if (v == 255.0f)  nf[3 + c]++;
                    else {
                        int b = (int)v;
                        atomicAdd(&lcnt[(3 + c) * NBINS + b], 1);
                    }
                }
            }
        }
    }

    // wave-reduce the 12 register counters, one LDS atomic per wave each
    #pragma unroll
    for (int j = 0; j < 6; ++j) {
        int a = nz[j], f = nf[j];
        #pragma unroll
        for (int off = 32; off > 0; off >>= 1) {
            a += __shfl_down(a, off, 64);
            f += __shfl_down(f, off, 64);
        }
        if ((threadIdx.x & 63) == 0) {
            if (a) atomicAdd(&lcnt[j * NBINS + 0], a);
            if (f) atomicAdd(&lcnt[j * NBINS + NBINS - 1], f);
        }
    }
    __syncthreads();

    // coalesced flush of this block's partial row (full overwrite -> no memset)
    int* row = parts + (size_t)blockIdx.x * ROW_DWORDS;
    for (int i = threadIdx.x; i < ROW_DWORDS; i += blockDim.x)
        row[i] = (i < 6 * NBINS) ? lcnt[i] : __float_as_int(lsum[i - 6 * NBINS]);
}

// Kernel 2: column reduction, parallelized over row-chunks.
// grid = (ceil(2304/256), nchunks); one atomic per (column, chunk).
__global__ void reduce_kernel(const int* __restrict__ parts, int nblk,
                              int* __restrict__ counts,
                              double* __restrict__ sums) {
    const int j = blockIdx.x * blockDim.x + threadIdx.x;   // column 0..2303
    if (j >= ROW_DWORDS) return;
    int w0 = blockIdx.y * ROWS_PER_CHUNK;
    int w1 = w0 + ROWS_PER_CHUNK;
    if (w1 > nblk) w1 = nblk;
    if (w0 >= w1) return;

    if (j < 6 * NBINS) {
        int acc = 0;
        for (int w = w0; w < w1; ++w) acc += parts[(size_t)w * ROW_DWORDS + j];
        if (acc) atomicAdd(&counts[j], acc);
    } else {
        double acc = 0.0;
        for (int w = w0; w < w1; ++w)
            acc += (double)__int_as_float(parts[(size_t)w * ROW_DWORDS + j]);
        if (acc != 0.0) atomicAdd(&sums[j - 6 * NBINS], acc);
    }
}

// Kernel 3: cdf (bit-exact serial f32 cumsum) + searchsorted table + analytic loss.
// Within bin b, v in [b, b+1) and t integer => |v-t| sign fixed per bin:
//   t <= b : sum = s_b - n_b*t ;  t >= b+1 : sum = n_b*t - s_b.
__global__ void final_kernel(const int* __restrict__ counts,
                             const double* __restrict__ sums,
                             float* __restrict__ out) {
    __shared__ float cdf[6][NBINS];
    __shared__ int   lcnt[6 * NBINS];
    __shared__ double red[12];
    const int tid = threadIdx.x;           // 768 threads
    lcnt[tid]       = counts[tid];
    lcnt[tid + 768] = counts[tid + 768];
    __syncthreads();

    if (tid < 6) {
        // pdf = count / 2^20 is exact; serial f32 cumsum matches the reference
        float run = 0.0f;
        for (int i = 0; i < NBINS; ++i) {
            run += (float)lcnt[tid * NBINS + i] * (1.0f / KCNT);
            cdf[tid][i] = run;
        }
    }
    __syncthreads();

    const int c = tid >> 8, b = tid & (NBINS - 1);
    const float d = cdf[c][b];
    const float* r = cdf[3 + c];
    // searchsorted(r, d, side='left'): first j with r[j] >= d
    int lo = 0, hi = NBINS;
    while (lo < hi) {
        int mid = (lo + hi) >> 1;
        if (r[mid] < d) lo = mid + 1; else hi = mid;
    }
    int j = lo;
    if (j < 1) j = 1;
    if (j > NBINS - 1) j = NBINS - 1;
    bool valid = (r[j - 1] <= d) && (d <= r[j]);
    int t = valid ? j : b;
    if (b == NBINS - 1) t = NBINS - 1;

    const int n = lcnt[c * NBINS + b];
    const double s = (b == NBINS - 1) ? 255.0 * (double)n : sums[c * NBINS + b];
    double contrib = (t <= b) ? (s - (double)n * (double)t)
                              : ((double)n * (double)t - s);

    #pragma unroll
    for (int off = 32; off > 0; off >>= 1)
        contrib += __shfl_down(contrib, off, 64);
    const int wave = tid >> 6, lane = tid & 63;
    if (lane == 0) red[wave] = contrib;
    __syncthreads();
    if (tid == 0) {
        double tot = 0.0;
        for (int w = 0; w < 12; ++w) tot += red[w];
        out[0] = (float)(tot / TOTAL_ELEMS);
    }
}

extern "C" void kernel_launch(void* const* d_in, const int* in_sizes, int n_in,
                              void* d_out, int out_size, void* d_ws, size_t ws_size,
                              hipStream_t stream) {
    const float* inp  = (const float*)d_in[0];   // (1,3,H,H)
    const float* tar  = (const float*)d_in[1];   // (1,3,H,H)
    const float* msrc = (const float*)d_in[2];   // (1,1,H,H)
    const float* mtar = (const float*)d_in[3];   // (1,1,H,H)
    float* out = (float*)d_out;

    int nblk = 1024;
    if (ws_size < (size_t)nblk * ROW_BYTES + TAIL_BYTES) {
        size_t avail = ws_size > TAIL_BYTES ? (ws_size - TAIL_BYTES) / ROW_BYTES : 1;
        nblk = avail < 1 ? 1 : (int)avail;
    }

    char* ws = (char*)d_ws;
    int*    parts  = (int*)ws;
    int*    counts = (int*)(ws + (size_t)nblk * ROW_BYTES);
    double* sums   = (double*)(ws + (size_t)nblk * ROW_BYTES + 6 * NBINS * sizeof(int));

    // zero only the small accumulator tail (atomic destinations)
    hipMemsetAsync((void*)counts, 0, TAIL_BYTES, stream);

    const int nchunks = (nblk + ROWS_PER_CHUNK - 1) / ROWS_PER_CHUNK;
    dim3 rgrid((ROW_DWORDS + 255) / 256, nchunks);

    hist_kernel<<<nblk, 256, 0, stream>>>(inp, tar, msrc, mtar, parts);
    reduce_kernel<<<rgrid, 256, 0, stream>>>(parts, nblk, counts, sums);
    final_kernel<<<1, 3 * NBINS, 0, stream>>>(counts, sums, out);
}